// Round 1
// baseline (174.741 us; speedup 1.0000x reference)
//
#include <hip/hip_runtime.h>

#define B 8192
#define F 128
#define H 64

// One thread per (b, f). f is wave-uniform (blockIdx.y) so all W1/b1/W2/b2/W3/b3
// accesses are uniform -> scalar loads (s_load) feeding v_fmac_f32 v,s,v.
// acc[64] + h1 chunk in VGPRs; hc loop kept dynamic to bound I-cache footprint.
__global__ __launch_bounds__(256) void nam_main(
    const float* __restrict__ inputs, const float* __restrict__ W1,
    const float* __restrict__ b1, const float* __restrict__ W2,
    const float* __restrict__ b2, const float* __restrict__ W3,
    const float* __restrict__ b3, float* __restrict__ fnn_out)
{
    const int b = blockIdx.x * 256 + threadIdx.x;
    const int f = blockIdx.y;

    const float x = inputs[(size_t)b * F + f];

    const float* W1f = W1 + f * H;
    const float* b1f = b1 + f * H;
    const float* W2f = W2 + (size_t)f * H * H;
    const float* b2f = b2 + f * H;
    const float* W3f = W3 + f * H;

    float acc[H];
#pragma unroll
    for (int k = 0; k < H; ++k) acc[k] = b2f[k];

#pragma unroll 1
    for (int hc = 0; hc < H / 8; ++hc) {
        float h1v[8];
#pragma unroll
        for (int i = 0; i < 8; ++i) {
            const int h = hc * 8 + i;
            h1v[i] = fmaxf(fmaf(x, W1f[h], b1f[h]), 0.0f);
        }
#pragma unroll
        for (int i = 0; i < 8; ++i) {
            const float* w2row = W2f + (size_t)(hc * 8 + i) * H;
#pragma unroll
            for (int k = 0; k < H; ++k)
                acc[k] = fmaf(h1v[i], w2row[k], acc[k]);
        }
    }

    float fnn = b3[f];
#pragma unroll
    for (int k = 0; k < H; ++k)
        fnn = fmaf(fmaxf(acc[k], 0.0f), W3f[k], fnn);

    fnn_out[(size_t)b * F + f] = fnn;
}

// out[b] = sum_f fnn[b][f].  32 lanes x float4 cover one 128-col row (512 B
// contiguous -> coalesced); 8 rows per 256-thread block; shfl reduce width 32.
__global__ __launch_bounds__(256) void nam_reduce(
    const float* __restrict__ fnn, float* __restrict__ out)
{
    const int tid = threadIdx.x;
    const int r = tid >> 5;   // row within block, 0..7
    const int c = tid & 31;   // float4 column, 0..31
    const int b = blockIdx.x * 8 + r;

    const float4* row = (const float4*)(fnn + (size_t)b * F);
    float4 v = row[c];
    float s = v.x + v.y + v.z + v.w;
#pragma unroll
    for (int off = 16; off > 0; off >>= 1)
        s += __shfl_down(s, off, 32);
    if (c == 0) out[b] = s;
}

extern "C" void kernel_launch(void* const* d_in, const int* in_sizes, int n_in,
                              void* d_out, int out_size, void* d_ws, size_t ws_size,
                              hipStream_t stream) {
    const float* inputs = (const float*)d_in[0];
    const float* W1     = (const float*)d_in[1];
    const float* b1     = (const float*)d_in[2];
    const float* W2     = (const float*)d_in[3];
    const float* b2     = (const float*)d_in[4];
    const float* W3     = (const float*)d_in[5];
    const float* b3     = (const float*)d_in[6];

    float* out = (float*)d_out;   // (B,)
    float* fnn = out + B;         // (B, F) region of the concatenated output

    nam_main<<<dim3(B / 256, F), 256, 0, stream>>>(inputs, W1, b1, W2, b2, W3,
                                                   b3, fnn);
    nam_reduce<<<dim3(B / 8), 256, 0, stream>>>(fnn, out);
}

// Round 2
// 173.466 us; speedup vs baseline: 1.0073x; 1.0073x over previous
//
#include <hip/hip_runtime.h>

#define B 8192
#define F 128
#define H 64

// One thread per (b, f); f = blockIdx.y is wave-uniform so all weight accesses
// are scalar (s_load) feeding v_fmac_f32 v,s,v.
// k tiled in chunks of 32 so live regs = acc[32] + few => stays in arch VGPRs
// (R1's acc[64] version got VGPR=36 + AGPR shuffles: 120us, VALUBusy 61%).
// Layer-1 h1 recomputed per chunk (+1.5% FMAs), layer-3 folded into epilogue.
__global__ __launch_bounds__(256) void nam_main(
    const float* __restrict__ inputs, const float* __restrict__ W1,
    const float* __restrict__ b1, const float* __restrict__ W2,
    const float* __restrict__ b2, const float* __restrict__ W3,
    const float* __restrict__ b3, float* __restrict__ fnn_out)
{
    const int b = blockIdx.x * 256 + threadIdx.x;
    const int f = blockIdx.y;

    const float x = inputs[(size_t)b * F + f];

    const float* W1f = W1 + f * H;
    const float* b1f = b1 + f * H;
    const float* W2f = W2 + (size_t)f * H * H;
    const float* b2f = b2 + f * H;
    const float* W3f = W3 + f * H;

    float fnn = b3[f];

#pragma unroll 1
    for (int kc = 0; kc < H; kc += 32) {
        float acc[32];
#pragma unroll
        for (int k = 0; k < 32; ++k) acc[k] = b2f[kc + k];

#pragma unroll 4
        for (int h = 0; h < H; ++h) {
            const float h1 = fmaxf(fmaf(x, W1f[h], b1f[h]), 0.0f);
            const float* w2 = W2f + (size_t)h * H + kc;
#pragma unroll
            for (int k = 0; k < 32; ++k)
                acc[k] = fmaf(h1, w2[k], acc[k]);
        }

#pragma unroll
        for (int k = 0; k < 32; ++k)
            fnn = fmaf(fmaxf(acc[k], 0.0f), W3f[kc + k], fnn);
    }

    fnn_out[(size_t)b * F + f] = fnn;
}

// out[b] = sum_f fnn[b][f].  32 lanes x float4 cover one 128-col row (512 B
// contiguous -> coalesced); 8 rows per 256-thread block; shfl reduce width 32.
__global__ __launch_bounds__(256) void nam_reduce(
    const float* __restrict__ fnn, float* __restrict__ out)
{
    const int tid = threadIdx.x;
    const int r = tid >> 5;   // row within block, 0..7
    const int c = tid & 31;   // float4 column, 0..31
    const int b = blockIdx.x * 8 + r;

    const float4* row = (const float4*)(fnn + (size_t)b * F);
    float4 v = row[c];
    float s = v.x + v.y + v.z + v.w;
#pragma unroll
    for (int off = 16; off > 0; off >>= 1)
        s += __shfl_down(s, off, 32);
    if (c == 0) out[b] = s;
}

extern "C" void kernel_launch(void* const* d_in, const int* in_sizes, int n_in,
                              void* d_out, int out_size, void* d_ws, size_t ws_size,
                              hipStream_t stream) {
    const float* inputs = (const float*)d_in[0];
    const float* W1     = (const float*)d_in[1];
    const float* b1     = (const float*)d_in[2];
    const float* W2     = (const float*)d_in[3];
    const float* b2     = (const float*)d_in[4];
    const float* W3     = (const float*)d_in[5];
    const float* b3     = (const float*)d_in[6];

    float* out = (float*)d_out;   // (B,)
    float* fnn = out + B;         // (B, F) region of the concatenated output

    nam_main<<<dim3(B / 256, F), 256, 0, stream>>>(inputs, W1, b1, W2, b2, W3,
                                                   b3, fnn);
    nam_reduce<<<dim3(B / 8), 256, 0, stream>>>(fnn, out);
}

// Round 3
// 112.814 us; speedup vs baseline: 1.5489x; 1.5376x over previous
//
#include <hip/hip_runtime.h>

#define B 8192
#define F 128
#define H 64

typedef __attribute__((ext_vector_type(8))) short bf16x8;
typedef __attribute__((ext_vector_type(4))) float f32x4;

static __device__ __forceinline__ unsigned short f32_to_bf16(float v) {
    unsigned int u = __float_as_uint(v);
    unsigned int r = (u + 0x7FFFu + ((u >> 16) & 1u)) >> 16;
    return (unsigned short)r;
}
static __device__ __forceinline__ float bf16_to_f32(unsigned short h) {
    return __uint_as_float(((unsigned int)h) << 16);
}

// Split-bf16 MFMA NAM: layer2 as 3x mfma_f32_16x16x32_bf16 (hi*hi + hi*lo +
// lo*hi; dropped lo*lo ~2^-18 rel).  One wg = one f x 256 batch rows, 4 waves
// x 4 m-tiles.  W2 staged to LDS in B-fragment order (lane-consecutive 16B ->
// conflict-free ds_read_b128); h1 computed in-lane directly in A-fragment
// layout (m=lane&15, k=quad*8+j) -> no LDS round-trip for A.  acc init = b2;
// layer3 relu*W3 + shfl_xor reduce in epilogue.
__global__ __launch_bounds__(256, 3) void nam_main(
    const float* __restrict__ inputs, const float* __restrict__ W1,
    const float* __restrict__ b1, const float* __restrict__ W2,
    const float* __restrict__ b2, const float* __restrict__ W3,
    const float* __restrict__ b3, float* __restrict__ fnn_out)
{
    const int tid = threadIdx.x;
    const int f = blockIdx.y;
    const int b0 = blockIdx.x * 256;

    const float* W1f = W1 + f * H;
    const float* b1f = b1 + f * H;
    const float* W2f = W2 + (size_t)f * H * H;
    const float* b2f = b2 + f * H;
    const float* W3f = W3 + f * H;

    // B-fragment store: slot = (nt*2+ks)*64 + lane, 8 bf16 per slot.
    __shared__ short bhi_s[512 * 8];   // 8 KB
    __shared__ short blo_s[512 * 8];   // 8 KB

    // ---- stage W2 -> hi/lo bf16 fragments (coalesced loads, b128 writes) ----
#pragma unroll
    for (int t = tid; t < 512; t += 256) {
        const int n = t & 63;          // output hidden index (MFMA n)
        const int g = t >> 6;          // h-group: h = g*8 + jj (MFMA k)
        const int nt = n >> 4, c = n & 15;
        const int ks = g >> 2, q = g & 3;
        const int slot = (nt * 2 + ks) * 64 + c + 16 * q;
        bf16x8 hv, lv;
#pragma unroll
        for (int jj = 0; jj < 8; ++jj) {
            const float wv = W2f[(g * 8 + jj) * H + n];
            const unsigned short hi = f32_to_bf16(wv);
            const unsigned short lo = f32_to_bf16(wv - bf16_to_f32(hi));
            hv[jj] = (short)hi;
            lv[jj] = (short)lo;
        }
        *(bf16x8*)&bhi_s[slot * 8] = hv;
        *(bf16x8*)&blo_s[slot * 8] = lv;
    }

    const int lane = tid & 63;
    const int w    = tid >> 6;
    const int q    = lane >> 4;   // quad
    const int col  = lane & 15;

    // per-lane layer-1 weights: k = ks*32 + q*8 + j
    float w1v[16], b1v[16];
#pragma unroll
    for (int ks = 0; ks < 2; ++ks)
#pragma unroll
        for (int j = 0; j < 8; ++j) {
            w1v[ks * 8 + j] = W1f[ks * 32 + q * 8 + j];
            b1v[ks * 8 + j] = b1f[ks * 32 + q * 8 + j];
        }
    float b2v[4], w3v[4];
#pragma unroll
    for (int nt = 0; nt < 4; ++nt) {
        b2v[nt] = b2f[nt * 16 + col];
        w3v[nt] = W3f[nt * 16 + col];
    }
    const float b3f = b3[f];

    __syncthreads();

    // ---- resident B fragments ----
    bf16x8 bhi[4][2], blo[4][2];
#pragma unroll
    for (int nt = 0; nt < 4; ++nt)
#pragma unroll
        for (int ks = 0; ks < 2; ++ks) {
            const int slot = (nt * 2 + ks) * 64 + lane;
            bhi[nt][ks] = *(bf16x8*)&bhi_s[slot * 8];
            blo[nt][ks] = *(bf16x8*)&blo_s[slot * 8];
        }

    // ---- 4 m-tiles of 16 rows per wave ----
#pragma unroll 1
    for (int mt = 0; mt < 4; ++mt) {
        const int rbase = b0 + w * 64 + mt * 16;
        const float x = inputs[(size_t)(rbase + col) * F + f];

        f32x4 acc[4];
#pragma unroll
        for (int nt = 0; nt < 4; ++nt) {
            acc[nt][0] = b2v[nt]; acc[nt][1] = b2v[nt];
            acc[nt][2] = b2v[nt]; acc[nt][3] = b2v[nt];
        }

#pragma unroll
        for (int ks = 0; ks < 2; ++ks) {
            bf16x8 ahi, alo;
#pragma unroll
            for (int j = 0; j < 8; ++j) {
                float h1 = fmaxf(fmaf(x, w1v[ks * 8 + j], b1v[ks * 8 + j]), 0.0f);
                const unsigned short hi = f32_to_bf16(h1);
                const unsigned short lo = f32_to_bf16(h1 - bf16_to_f32(hi));
                ahi[j] = (short)hi;
                alo[j] = (short)lo;
            }
#pragma unroll
            for (int nt = 0; nt < 4; ++nt) {
                acc[nt] = __builtin_amdgcn_mfma_f32_16x16x32_bf16(ahi, bhi[nt][ks], acc[nt], 0, 0, 0);
                acc[nt] = __builtin_amdgcn_mfma_f32_16x16x32_bf16(ahi, blo[nt][ks], acc[nt], 0, 0, 0);
                acc[nt] = __builtin_amdgcn_mfma_f32_16x16x32_bf16(alo, bhi[nt][ks], acc[nt], 0, 0, 0);
            }
        }

        // ---- epilogue: fnn[row] = sum_n relu(C)*W3[n] + b3 ----
        float s[4];
#pragma unroll
        for (int reg = 0; reg < 4; ++reg) {
            float t = 0.0f;
#pragma unroll
            for (int nt = 0; nt < 4; ++nt)
                t = fmaf(fmaxf(acc[nt][reg], 0.0f), w3v[nt], t);
            s[reg] = t;
        }
#pragma unroll
        for (int m_ = 1; m_ <= 8; m_ <<= 1)
#pragma unroll
            for (int reg = 0; reg < 4; ++reg)
                s[reg] += __shfl_xor(s[reg], m_, 64);
        if (col == 0) {
#pragma unroll
            for (int reg = 0; reg < 4; ++reg)
                fnn_out[(size_t)(rbase + 4 * q + reg) * F + f] = s[reg] + b3f;
        }
    }
}

// out[b] = sum_f fnn[b][f].
__global__ __launch_bounds__(256) void nam_reduce(
    const float* __restrict__ fnn, float* __restrict__ out)
{
    const int tid = threadIdx.x;
    const int r = tid >> 5;
    const int c = tid & 31;
    const int b = blockIdx.x * 8 + r;

    const float4* row = (const float4*)(fnn + (size_t)b * F);
    float4 v = row[c];
    float s = v.x + v.y + v.z + v.w;
#pragma unroll
    for (int off = 16; off > 0; off >>= 1)
        s += __shfl_down(s, off, 32);
    if (c == 0) out[b] = s;
}

extern "C" void kernel_launch(void* const* d_in, const int* in_sizes, int n_in,
                              void* d_out, int out_size, void* d_ws, size_t ws_size,
                              hipStream_t stream) {
    const float* inputs = (const float*)d_in[0];
    const float* W1     = (const float*)d_in[1];
    const float* b1     = (const float*)d_in[2];
    const float* W2     = (const float*)d_in[3];
    const float* b2     = (const float*)d_in[4];
    const float* W3     = (const float*)d_in[5];
    const float* b3     = (const float*)d_in[6];

    float* out = (float*)d_out;   // (B,)
    float* fnn = out + B;         // (B, F)

    nam_main<<<dim3(B / 256, F), 256, 0, stream>>>(inputs, W1, b1, W2, b2, W3,
                                                   b3, fnn);
    nam_reduce<<<dim3(B / 8), 256, 0, stream>>>(fnn, out);
}

// Round 4
// 107.750 us; speedup vs baseline: 1.6217x; 1.0470x over previous
//
#include <hip/hip_runtime.h>

#define B 8192
#define F 128
#define H 64

typedef __attribute__((ext_vector_type(8))) short bf16x8;
typedef __attribute__((ext_vector_type(4))) float f32x4;

static __device__ __forceinline__ unsigned short f32_to_bf16_rne(float v) {
    unsigned int u = __float_as_uint(v);
    unsigned int r = (u + 0x7FFFu + ((u >> 16) & 1u)) >> 16;
    return (unsigned short)r;
}
static __device__ __forceinline__ float bf16_to_f32(unsigned short h) {
    return __uint_as_float(((unsigned int)h) << 16);
}

// Split-bf16 MFMA NAM.  Layer2 = 3x mfma_f32_16x16x32_bf16 (hh + hl + lh).
// R4: A-operand split is truncation-based Dekker (hi = u&0xFFFF0000 exact in
// bf16, lo = r-hi exact; pack pairs with v_perm) -> ~4.5 VALU/h1 vs ~14 for
// software-RNE (R3 was VALU-bound: 58% VALUBusy vs 19% MfmaUtil).  x gather
// hoisted above the barrier.  Reduction over f fused via atomicAdd (out
// zeroed by memsetAsync); nam_reduce launch eliminated.
__global__ __launch_bounds__(256, 3) void nam_main(
    const float* __restrict__ inputs, const float* __restrict__ W1,
    const float* __restrict__ b1, const float* __restrict__ W2,
    const float* __restrict__ b2, const float* __restrict__ W3,
    const float* __restrict__ b3, float* __restrict__ out,
    float* __restrict__ fnn_out)
{
    const int tid = threadIdx.x;
    const int f = blockIdx.y;
    const int b0 = blockIdx.x * 256;

    const float* W1f = W1 + f * H;
    const float* b1f = b1 + f * H;
    const float* W2f = W2 + (size_t)f * H * H;
    const float* b2f = b2 + f * H;
    const float* W3f = W3 + f * H;

    // B-fragment store: slot = (nt*2+ks)*64 + lane, 8 bf16 per slot.
    __shared__ short bhi_s[512 * 8];   // 8 KB
    __shared__ short blo_s[512 * 8];   // 8 KB

    // ---- stage W2 -> hi/lo bf16 B-fragments (RNE; one-time, off hot path) ----
#pragma unroll
    for (int t = tid; t < 512; t += 256) {
        const int n = t & 63;          // output hidden index (MFMA n)
        const int g = t >> 6;          // h-group: h = g*8 + jj (MFMA k)
        const int nt = n >> 4, c = n & 15;
        const int ks = g >> 2, q = g & 3;
        const int slot = (nt * 2 + ks) * 64 + c + 16 * q;
        bf16x8 hv, lv;
#pragma unroll
        for (int jj = 0; jj < 8; ++jj) {
            const float wv = W2f[(g * 8 + jj) * H + n];
            const unsigned short hi = f32_to_bf16_rne(wv);
            const unsigned short lo = f32_to_bf16_rne(wv - bf16_to_f32(hi));
            hv[jj] = (short)hi;
            lv[jj] = (short)lo;
        }
        *(bf16x8*)&bhi_s[slot * 8] = hv;
        *(bf16x8*)&blo_s[slot * 8] = lv;
    }

    const int lane = tid & 63;
    const int w    = tid >> 6;
    const int q    = lane >> 4;   // quad
    const int col  = lane & 15;

    // per-lane layer-1 weights: k = ks*32 + q*8 + j
    float w1v[16], b1v[16];
#pragma unroll
    for (int ks = 0; ks < 2; ++ks)
#pragma unroll
        for (int j = 0; j < 8; ++j) {
            w1v[ks * 8 + j] = W1f[ks * 32 + q * 8 + j];
            b1v[ks * 8 + j] = b1f[ks * 32 + q * 8 + j];
        }
    float b2v[4], w3v[4];
#pragma unroll
    for (int nt = 0; nt < 4; ++nt) {
        b2v[nt] = b2f[nt * 16 + col];
        w3v[nt] = W3f[nt * 16 + col];
    }
    const float b3f = b3[f];

    // hoist all 4 m-tiles' x gathers above the barrier (latency overlap)
    float x4[4];
#pragma unroll
    for (int mt = 0; mt < 4; ++mt)
        x4[mt] = inputs[(size_t)(b0 + w * 64 + mt * 16 + col) * F + f];

    __syncthreads();

    // ---- resident B fragments ----
    bf16x8 bhi[4][2], blo[4][2];
#pragma unroll
    for (int nt = 0; nt < 4; ++nt)
#pragma unroll
        for (int ks = 0; ks < 2; ++ks) {
            const int slot = (nt * 2 + ks) * 64 + lane;
            bhi[nt][ks] = *(bf16x8*)&bhi_s[slot * 8];
            blo[nt][ks] = *(bf16x8*)&blo_s[slot * 8];
        }

    // ---- 4 m-tiles of 16 rows per wave ----
#pragma unroll 1
    for (int mt = 0; mt < 4; ++mt) {
        const int rbase = b0 + w * 64 + mt * 16;
        const float x = x4[mt];

        f32x4 acc[4];
#pragma unroll
        for (int nt = 0; nt < 4; ++nt) {
            acc[nt][0] = b2v[nt]; acc[nt][1] = b2v[nt];
            acc[nt][2] = b2v[nt]; acc[nt][3] = b2v[nt];
        }

#pragma unroll
        for (int ks = 0; ks < 2; ++ks) {
            // A-frag: trunc-Dekker split, v_perm pair-packing.
            union { unsigned int u[4]; bf16x8 v; } Ah, Al;
#pragma unroll
            for (int t = 0; t < 4; ++t) {
                const float r0 = fmaxf(fmaf(x, w1v[ks * 8 + 2 * t],     b1v[ks * 8 + 2 * t]),     0.0f);
                const float r1 = fmaxf(fmaf(x, w1v[ks * 8 + 2 * t + 1], b1v[ks * 8 + 2 * t + 1]), 0.0f);
                const unsigned int u0 = __float_as_uint(r0);
                const unsigned int u1 = __float_as_uint(r1);
                const float l0 = r0 - __uint_as_float(u0 & 0xFFFF0000u);
                const float l1 = r1 - __uint_as_float(u1 & 0xFFFF0000u);
                Ah.u[t] = __builtin_amdgcn_perm(u1, u0, 0x07060302);
                Al.u[t] = __builtin_amdgcn_perm(__float_as_uint(l1),
                                                __float_as_uint(l0), 0x07060302);
            }
#pragma unroll
            for (int nt = 0; nt < 4; ++nt) {
                acc[nt] = __builtin_amdgcn_mfma_f32_16x16x32_bf16(Ah.v, bhi[nt][ks], acc[nt], 0, 0, 0);
                acc[nt] = __builtin_amdgcn_mfma_f32_16x16x32_bf16(Ah.v, blo[nt][ks], acc[nt], 0, 0, 0);
                acc[nt] = __builtin_amdgcn_mfma_f32_16x16x32_bf16(Al.v, bhi[nt][ks], acc[nt], 0, 0, 0);
            }
        }

        // ---- epilogue: fnn[row] = sum_n relu(C)*W3[n] + b3; out[row] += fnn ----
        float s[4];
#pragma unroll
        for (int reg = 0; reg < 4; ++reg) {
            float t = 0.0f;
#pragma unroll
            for (int nt = 0; nt < 4; ++nt)
                t = fmaf(fmaxf(acc[nt][reg], 0.0f), w3v[nt], t);
            s[reg] = t;
        }
#pragma unroll
        for (int m_ = 1; m_ <= 8; m_ <<= 1)
#pragma unroll
            for (int reg = 0; reg < 4; ++reg)
                s[reg] += __shfl_xor(s[reg], m_, 64);
        if (col == 0) {
#pragma unroll
            for (int reg = 0; reg < 4; ++reg) {
                const int row = rbase + 4 * q + reg;
                const float val = s[reg] + b3f;
                fnn_out[(size_t)row * F + f] = val;
                atomicAdd(&out[row], val);
            }
        }
    }
}

extern "C" void kernel_launch(void* const* d_in, const int* in_sizes, int n_in,
                              void* d_out, int out_size, void* d_ws, size_t ws_size,
                              hipStream_t stream) {
    const float* inputs = (const float*)d_in[0];
    const float* W1     = (const float*)d_in[1];
    const float* b1     = (const float*)d_in[2];
    const float* W2     = (const float*)d_in[3];
    const float* b2     = (const float*)d_in[4];
    const float* W3     = (const float*)d_in[5];
    const float* b3     = (const float*)d_in[6];

    float* out = (float*)d_out;   // (B,)
    float* fnn = out + B;         // (B, F)

    hipMemsetAsync(out, 0, B * sizeof(float), stream);
    nam_main<<<dim3(B / 256, F), 256, 0, stream>>>(inputs, W1, b1, W2, b2, W3,
                                                   b3, out, fnn);
}